// Round 8
// baseline (300.889 us; speedup 1.0000x reference)
//
#include <hip/hip_runtime.h>

// HIGNN, round 22 = R21 (285us, p1=106) with:
//  - p1 KPT 4->8 (SPAN 2048): weight ds_reads + rank/reserve/staging amortize
//    over 2x edges; 8 in-flight x4 gathers per thread (latency hiding).
//  - p2 wave-private LDS tiles (16 x 6KB = 96KB, 1 block/CU): kills
//    cross-wave LDS atomic contention; 16-tile merge at end.
// Frozen: 3-dispatch skeleton, no-histogram rank/reserve/append, packed fp16
// weights in LDS, parity interleave.
// LESSONS: agent fences per block = 6x poison (R19/20); global fp32 atomics
// to shared out = HBM RMW (R18); weights belong in LDS (R15).

constexpr int HIDDEN = 64;
constexpr int NB_MAX = 256;      // bucket bins (>= nbuckets), == BLK
constexpr int NPB_SHIFT = 9;     // 512 nodes per bucket
constexpr int NPB = 1 << NPB_SHIFT;
constexpr int TILE_F = NPB * 3;  // floats per bucket tile (1536)
constexpr int NET_SLOT = 1040;   // dwords per packed-net slot
constexpr int BLK = 256;
constexpr int KPT = 8;           // edges per thread (R22: 4->8)

typedef _Float16 h2_t __attribute__((ext_vector_type(2)));

__device__ __forceinline__ unsigned packh2(float a, float b) {
    auto h = __builtin_amdgcn_cvt_pkrtz(a, b);   // __fp16 ext_vector(2)
    return __builtin_bit_cast(unsigned, h);
}
__device__ __forceinline__ float fdot2u(unsigned a, unsigned b, float c) {
    h2_t ha = __builtin_bit_cast(h2_t, a);
    h2_t hb = __builtin_bit_cast(h2_t, b);
#if __has_builtin(__builtin_amdgcn_fdot2)
    return __builtin_amdgcn_fdot2(ha, hb, c, false);
#else
    return fmaf((float)ha.x, (float)hb.x, fmaf((float)ha.y, (float)hb.y, c));
#endif
}

// Packed net slot layout (dword indices within NET_SLOT):
// din3 nets (2body, self): row per hh2 at h2*16 (64B aligned):
//   [0]=wA  [1]=wB  [2]=b1A f32  [3]=b1B f32  [4]=w1cA f32  [5]=w1cB f32
//   [6..14]=w2p[0..8] packed     [15]=pad
// din6 net (3body): row per hh2 at h2*32 (128B aligned):
//   [0..2]=wA0..2  [3..5]=wB0..2  [6]=b1A  [7]=b1B  [8..16]=w2p  [17..31]=pad
// all nets: [1024..1032] = b2[0..8] f32

// ---------------- Setup: pack 3 nets + zero gcount + pad x ----------------
__global__ __launch_bounds__(256) void setup_kernel(
    const float* __restrict__ x, int n_nodes, float4* __restrict__ x4,
    int* __restrict__ gcount,
    const float* __restrict__ W1_2b, const float* __restrict__ b1_2b,
    const float* __restrict__ W2_2b, const float* __restrict__ b2_2b,
    const float* __restrict__ W1_s,  const float* __restrict__ b1_s,
    const float* __restrict__ W2_s,  const float* __restrict__ b2_s,
    const float* __restrict__ W1_3b, const float* __restrict__ b1_3b,
    const float* __restrict__ W2_3b, const float* __restrict__ b2_3b,
    unsigned* __restrict__ nets)
{
    const int blk = blockIdx.x;
    const int tid = threadIdx.x;
    if (blk < 3) {
        const float *W1, *b1, *W2, *b2; int din;
        if (blk == 0) { W1 = W1_2b; b1 = b1_2b; W2 = W2_2b; b2 = b2_2b; din = 3; }
        else if (blk == 1) { W1 = W1_s; b1 = b1_s; W2 = W2_s; b2 = b2_s; din = 3; }
        else { W1 = W1_3b; b1 = b1_3b; W2 = W2_3b; b2 = b2_3b; din = 6; }
        unsigned* slot = nets + blk * NET_SLOT;
        float* slotf = (float*)slot;
        if (tid < 32) {
            const int h2 = tid, hA = 2 * h2, hB = 2 * h2 + 1;
            if (din == 3) {
                unsigned* row = slot + h2 * 16;
                float* rowf = (float*)row;
                row[0] = packh2(W1[0 * HIDDEN + hA], W1[1 * HIDDEN + hA]);
                row[1] = packh2(W1[0 * HIDDEN + hB], W1[1 * HIDDEN + hB]);
                rowf[2] = b1[hA]; rowf[3] = b1[hB];
                rowf[4] = W1[2 * HIDDEN + hA]; rowf[5] = W1[2 * HIDDEN + hB];
                #pragma unroll
                for (int i = 0; i < 9; ++i)
                    row[6 + i] = packh2(W2[hA * 9 + i], W2[hB * 9 + i]);
                row[15] = 0;
            } else {
                unsigned* row = slot + h2 * 32;
                float* rowf = (float*)row;
                #pragma unroll
                for (int r = 0; r < 3; ++r) {
                    row[r]     = packh2(W1[(2 * r) * HIDDEN + hA], W1[(2 * r + 1) * HIDDEN + hA]);
                    row[3 + r] = packh2(W1[(2 * r) * HIDDEN + hB], W1[(2 * r + 1) * HIDDEN + hB]);
                }
                rowf[6] = b1[hA]; rowf[7] = b1[hB];
                #pragma unroll
                for (int i = 0; i < 9; ++i)
                    row[8 + i] = packh2(W2[hA * 9 + i], W2[hB * 9 + i]);
                #pragma unroll
                for (int i = 17; i < 20; ++i) row[i] = 0;
            }
        }
        if (tid >= 32 && tid < 41) slotf[1024 + (tid - 32)] = b2[tid - 32];
        if (blk == 0) gcount[tid] = 0;   // zeroes all NB_MAX bins
    } else {
        int i = (blk - 3) * 256 + tid;
        if (i < n_nodes)
            x4[i] = make_float4(x[3 * i], x[3 * i + 1], x[3 * i + 2], 0.0f);
    }
}

// ---------------- Phase 1: MLP -> rank -> reserve -> append ----------------
__global__ __launch_bounds__(256) void p1_edge_kernel(
    const float4* __restrict__ x4,
    const int* __restrict__ e0, long long E0, const float* __restrict__ at0,
    const int* __restrict__ e1, long long E1, const float* __restrict__ at1,
    const int* __restrict__ e2, long long E2, const float* __restrict__ at2,
    int g0, int g1,
    const unsigned* __restrict__ nets,
    float4* __restrict__ records, int* __restrict__ gcount, int cap)
{
    static_assert(NB_MAX == BLK, "one reserve bin per thread");
    __shared__ __align__(16) unsigned s_net[1033];   // rows + b2, ~4.1 KB
    __shared__ int s_rank[NB_MAX];
    __shared__ int s_base[NB_MAX];

    // ---- parity-interleaved block -> (set, tile) mapping ----
    const int gA = g0 + g1;
    const int gB = (int)gridDim.x - gA;
    const int mn = (gA < gB) ? gA : gB;
    int aidx = -1, b6 = -1;
    {
        const int idx = blockIdx.x;
        if (idx < 2 * mn) { if (idx & 1) b6 = idx >> 1; else aidx = idx >> 1; }
        else {
            const int r = idx - 2 * mn;
            if (gA > gB) aidx = mn + r; else b6 = mn + r;
        }
    }

    const int* edges; long long E; const float* attr;
    int bidx, nblk, din3;
    const unsigned* wp;
    if (aidx >= 0) {
        if (aidx < g0) { edges = e0; E = E0; attr = at0; bidx = aidx;      nblk = g0; din3 = 1; wp = nets; }
        else           { edges = e1; E = E1; attr = at1; bidx = aidx - g0; nblk = g1; din3 = 1; wp = nets + NET_SLOT; }
    } else             { edges = e2; E = E2; attr = at2; bidx = b6;        nblk = gB; din3 = 0; wp = nets + 2 * NET_SLOT; }

    const int tid = threadIdx.x;
    constexpr int SPAN = BLK * KPT;   // 2048
    long long span = (E + nblk - 1) / nblk;
    span = (span + (SPAN - 1)) & ~(long long)(SPAN - 1);
    const long long lo = (long long)bidx * span;
    const long long hi = (lo + span < E) ? (lo + span) : E;
    if (lo >= E) return;

    const bool e_aligned = ((E & 3) == 0);

    s_rank[tid] = 0;
    const int nstage = din3 ? 512 : 1024;
    for (int i = tid; i < nstage; i += BLK) s_net[i] = wp[i];
    if (tid < 9) s_net[1024 + tid] = wp[1024 + tid];
    __syncthreads();

    const unsigned* w = s_net;
    const float* wf = (const float*)s_net;
    float b2r[9];
    #pragma unroll
    for (int i = 0; i < 9; ++i) b2r[i] = wf[1024 + i];

    const long long be = lo + (long long)tid * KPT;   // 8-aligned

    unsigned dp[KPT][3];
    float    d2s[KPT];
    float    a[KPT][3];
    int      dst[KPT];
    bool     valid[KPT];
    int      i0[KPT], i1[KPT], i2[KPT];

    const bool lane_live = (be < hi);
    const bool full = lane_live && e_aligned && (be + KPT <= hi);
    if (full) {
        #pragma unroll
        for (int h = 0; h < 2; ++h) {
            int4 r0 = *(const int4*)(edges + be + 4 * h);
            int4 r1 = *(const int4*)(edges + E + be + 4 * h);
            i0[4*h+0] = r0.x; i0[4*h+1] = r0.y; i0[4*h+2] = r0.z; i0[4*h+3] = r0.w;
            i1[4*h+0] = r1.x; i1[4*h+1] = r1.y; i1[4*h+2] = r1.z; i1[4*h+3] = r1.w;
            if (!din3) {
                int4 r2 = *(const int4*)(edges + 2 * E + be + 4 * h);
                i2[4*h+0] = r2.x; i2[4*h+1] = r2.y; i2[4*h+2] = r2.z; i2[4*h+3] = r2.w;
            }
        }
        #pragma unroll
        for (int q = 0; q < 6; ++q) {
            float4 av = *(const float4*)(attr + 3 * be + 4 * q);
            a[(4*q+0)/3][(4*q+0)%3] = av.x;
            a[(4*q+1)/3][(4*q+1)%3] = av.y;
            a[(4*q+2)/3][(4*q+2)%3] = av.z;
            a[(4*q+3)/3][(4*q+3)%3] = av.w;
        }
        #pragma unroll
        for (int u = 0; u < KPT; ++u) valid[u] = true;
    } else {
        #pragma unroll
        for (int u = 0; u < KPT; ++u) {
            long long e = be + u;
            valid[u] = lane_live && (e < hi);
            long long ee = valid[u] ? e : lo;
            i0[u] = edges[ee];
            i1[u] = edges[E + ee];
            if (!din3) i2[u] = edges[2 * E + ee];
            #pragma unroll
            for (int c = 0; c < 3; ++c) a[u][c] = attr[3 * ee + c];
        }
    }

    // compute UNGUARDED (clamped lanes produce garbage; append is guarded)
    #pragma unroll
    for (int u = 0; u < KPT; ++u) {
        if (din3) {
            dst[u] = i1[u];
            float4 xs = x4[i0[u]];
            float4 xt = x4[i1[u]];
            dp[u][0] = packh2(xs.x - xt.x, xs.y - xt.y);
            d2s[u]   = xs.z - xt.z;
            dp[u][1] = 0; dp[u][2] = 0;
        } else {
            dst[u] = i2[u];
            float4 xj = x4[i0[u]];
            float4 xk = x4[i1[u]];
            float4 xi = x4[i2[u]];
            dp[u][0] = packh2(xk.x - xj.x, xk.y - xj.y);
            dp[u][1] = packh2(xk.z - xj.z, xi.x - xk.x);
            dp[u][2] = packh2(xi.y - xk.y, xi.z - xk.z);
            d2s[u] = 0.f;
        }
    }

    float acc[KPT][9];
    #pragma unroll
    for (int u = 0; u < KPT; ++u)
        #pragma unroll
        for (int i = 0; i < 9; ++i) acc[u][i] = b2r[i];

    if (din3) {
        for (int hh2 = 0; hh2 < HIDDEN / 2; ++hh2) {
            const uint4* rq = (const uint4*)(w + (hh2 << 4));
            const uint4 q0 = rq[0], q1 = rq[1], q2 = rq[2], q3 = rq[3];
            const unsigned wA = q0.x;
            const unsigned wB = q0.y;
            const float bbA = __uint_as_float(q0.z);
            const float bbB = __uint_as_float(q0.w);
            const float wcA = __uint_as_float(q1.x);
            const float wcB = __uint_as_float(q1.y);
            const unsigned w2p[9] = {q1.z, q1.w, q2.x, q2.y, q2.z,
                                     q2.w, q3.x, q3.y, q3.z};
            #pragma unroll
            for (int u = 0; u < KPT; ++u) {
                float preA = fmaf(d2s[u], wcA, fdot2u(dp[u][0], wA, bbA));
                float preB = fmaf(d2s[u], wcB, fdot2u(dp[u][0], wB, bbB));
                unsigned h2 = packh2(fmaxf(preA, 0.f), fmaxf(preB, 0.f));
                #pragma unroll
                for (int i = 0; i < 9; ++i)
                    acc[u][i] = fdot2u(h2, w2p[i], acc[u][i]);
            }
        }
    } else {
        for (int hh2 = 0; hh2 < HIDDEN / 2; ++hh2) {
            const uint4* rq = (const uint4*)(w + (hh2 << 5));
            const uint4 q0 = rq[0], q1 = rq[1], q2 = rq[2], q3 = rq[3];
            const unsigned q4x = w[(hh2 << 5) + 16];
            const unsigned wA0 = q0.x, wA1 = q0.y, wA2 = q0.z;
            const unsigned wB0 = q0.w, wB1 = q1.x, wB2 = q1.y;
            const float bbA = __uint_as_float(q1.z);
            const float bbB = __uint_as_float(q1.w);
            const unsigned w2p[9] = {q2.x, q2.y, q2.z, q2.w, q3.x,
                                     q3.y, q3.z, q3.w, q4x};
            #pragma unroll
            for (int u = 0; u < KPT; ++u) {
                float preA = fdot2u(dp[u][2], wA2,
                             fdot2u(dp[u][1], wA1,
                             fdot2u(dp[u][0], wA0, bbA)));
                float preB = fdot2u(dp[u][2], wB2,
                             fdot2u(dp[u][1], wB1,
                             fdot2u(dp[u][0], wB0, bbB)));
                unsigned h2 = packh2(fmaxf(preA, 0.f), fmaxf(preB, 0.f));
                #pragma unroll
                for (int i = 0; i < 9; ++i)
                    acc[u][i] = fdot2u(h2, w2p[i], acc[u][i]);
            }
        }
    }

    // rank: LDS atomics count per-bucket totals as a side effect
    int rk[KPT]; int bb[KPT];
    #pragma unroll
    for (int u = 0; u < KPT; ++u) {
        if (valid[u]) {
            bb[u] = dst[u] >> NPB_SHIFT;
            rk[u] = atomicAdd(&s_rank[bb[u]], 1);
        }
    }
    __syncthreads();

    // reserve per nonempty bin (one thread per bin), publish bases
    {
        int c = s_rank[tid];
        s_base[tid] = (c > 0) ? atomicAdd(&gcount[tid], c) : 0;
    }
    __syncthreads();

    #pragma unroll
    for (int u = 0; u < KPT; ++u) {
        if (!valid[u]) continue;
        float y0 = fmaf(acc[u][0], a[u][0], fmaf(acc[u][1], a[u][1], acc[u][2] * a[u][2]));
        float y1 = fmaf(acc[u][3], a[u][0], fmaf(acc[u][4], a[u][1], acc[u][5] * a[u][2]));
        float y2 = fmaf(acc[u][6], a[u][0], fmaf(acc[u][7], a[u][1], acc[u][8] * a[u][2]));
        int slot = s_base[bb[u]] + rk[u];
        if (slot < cap)
            records[(size_t)bb[u] * cap + slot] =
                make_float4(y0, y1, y2, __int_as_float(dst[u]));
    }
}

// ---------------- Phase 2: one block per bucket, wave-private tiles ----------------
__global__ __launch_bounds__(1024, 1) void p2_bucket(
    const float4* __restrict__ records, const int* __restrict__ gcount,
    int cap, int n_nodes, float* __restrict__ out)
{
    __shared__ float s_acc[16][TILE_F];   // 96 KB: one tile per wave
    const int b = blockIdx.x;
    const int tid = threadIdx.x;
    const int wv = tid >> 6;

    for (int i = tid; i < 16 * TILE_F; i += 1024)
        ((float*)s_acc)[i] = 0.0f;
    __syncthreads();

    int cnt = gcount[b];
    if (cnt > cap) cnt = cap;
    const float4* rb = records + (size_t)b * cap;
    float* my = s_acc[wv];
    for (int i = tid; i < cnt; i += 1024) {
        float4 r = rb[i];
        int loc = __float_as_int(r.w) - (b << NPB_SHIFT);
        atomicAdd(&my[loc * 3 + 0], r.x);
        atomicAdd(&my[loc * 3 + 1], r.y);
        atomicAdd(&my[loc * 3 + 2], r.z);
    }
    __syncthreads();

    const int start = (b << NPB_SHIFT) * 3;
    const int end = min(n_nodes * 3, ((b + 1) << NPB_SHIFT) * 3);
    for (int i = start + tid; i < end; i += 1024) {
        const int off = i - start;
        float s = 0.0f;
        #pragma unroll
        for (int wvi = 0; wvi < 16; ++wvi) s += s_acc[wvi][off];
        out[i] = s;
    }
}

// ---------------- Fallback: direct device atomics, fp32 ----------------
template <int DIN, int KPTF>
__global__ __launch_bounds__(256) void edge_mlp_atomic(
    const float* __restrict__ x,
    const int* __restrict__ edges, long long E,
    const float* __restrict__ attr,
    const float* __restrict__ W1, const float* __restrict__ b1,
    const float* __restrict__ W2, const float* __restrict__ b2,
    float* __restrict__ out)
{
    const int tid = threadIdx.x;
    const long long base = (long long)blockIdx.x * (blockDim.x * KPTF) + tid;
    float d[KPTF][DIN]; float a[KPTF][3]; int dst[KPTF]; bool valid[KPTF];
    #pragma unroll
    for (int u = 0; u < KPTF; ++u) {
        long long e = base + (long long)u * blockDim.x;
        valid[u] = (e < E);
        long long ee = valid[u] ? e : 0;
        if constexpr (DIN == 3) {
            int s = edges[ee]; int t = edges[E + ee]; dst[u] = t;
            #pragma unroll
            for (int c = 0; c < 3; ++c)
                d[u][c] = x[3 * (long long)s + c] - x[3 * (long long)t + c];
        } else {
            int j = edges[ee]; int k = edges[E + ee]; int i = edges[2 * E + ee];
            dst[u] = i;
            #pragma unroll
            for (int c = 0; c < 3; ++c) {
                float xj = x[3 * (long long)j + c];
                float xk = x[3 * (long long)k + c];
                float xi = x[3 * (long long)i + c];
                d[u][c] = xk - xj; d[u][3 + c] = xi - xk;
            }
        }
        #pragma unroll
        for (int c = 0; c < 3; ++c) a[u][c] = attr[3 * ee + c];
    }
    float acc[KPTF][9];
    #pragma unroll
    for (int u = 0; u < KPTF; ++u)
        #pragma unroll
        for (int i = 0; i < 9; ++i) acc[u][i] = b2[i];
    #pragma unroll 4
    for (int hh = 0; hh < HIDDEN; ++hh) {
        const float bb = b1[hh];
        float w1r[DIN];
        #pragma unroll
        for (int r = 0; r < DIN; ++r) w1r[r] = W1[r * HIDDEN + hh];
        float w2r[9];
        #pragma unroll
        for (int i = 0; i < 9; ++i) w2r[i] = W2[hh * 9 + i];
        #pragma unroll
        for (int u = 0; u < KPTF; ++u) {
            float pre = bb;
            #pragma unroll
            for (int r = 0; r < DIN; ++r) pre = fmaf(d[u][r], w1r[r], pre);
            const float h = fmaxf(pre, 0.0f);
            #pragma unroll
            for (int i = 0; i < 9; ++i) acc[u][i] = fmaf(h, w2r[i], acc[u][i]);
        }
    }
    #pragma unroll
    for (int u = 0; u < KPTF; ++u) {
        if (!valid[u]) continue;
        float* o = out + 3 * (long long)dst[u];
        #pragma unroll
        for (int i = 0; i < 3; ++i) {
            float y = fmaf(acc[u][3 * i + 0], a[u][0],
                      fmaf(acc[u][3 * i + 1], a[u][1],
                           acc[u][3 * i + 2] * a[u][2]));
            atomicAdd(&o[i], y);
        }
    }
}

extern "C" void kernel_launch(void* const* d_in, const int* in_sizes, int n_in,
                              void* d_out, int out_size, void* d_ws, size_t ws_size,
                              hipStream_t stream)
{
    const float* x  = (const float*)d_in[0];
    const int*   e2 = (const int*)d_in[1];
    const int*   e3 = (const int*)d_in[2];
    const int*   es = (const int*)d_in[3];
    const float* a2 = (const float*)d_in[5];
    const float* a3 = (const float*)d_in[6];
    const float* as = (const float*)d_in[7];
    const float* W1_2b = (const float*)d_in[9];
    const float* b1_2b = (const float*)d_in[10];
    const float* W2_2b = (const float*)d_in[11];
    const float* b2_2b = (const float*)d_in[12];
    const float* W1_3b = (const float*)d_in[13];
    const float* b1_3b = (const float*)d_in[14];
    const float* W2_3b = (const float*)d_in[15];
    const float* b2_3b = (const float*)d_in[16];
    const float* W1_s  = (const float*)d_in[17];
    const float* b1_s  = (const float*)d_in[18];
    const float* W2_s  = (const float*)d_in[19];
    const float* b2_s  = (const float*)d_in[20];

    const long long E2 = in_sizes[1] / 2;
    const long long E3 = in_sizes[2] / 3;
    const long long ES = in_sizes[3] / 2;
    const long long Etot = E2 + E3 + ES;
    const int n_nodes = out_size / 3;
    const int nbuckets = (n_nodes + NPB - 1) >> NPB_SHIFT;

    float* out = (float*)d_out;

    // ws layout: [gcount 1KB][nets][x4][records]
    const size_t off_nets = 1024;
    const size_t off_x4 = (off_nets + 3 * NET_SLOT * 4 + 255) & ~(size_t)255;
    const size_t x4_bytes = (size_t)n_nodes * sizeof(float4);
    const size_t off_rec = (off_x4 + x4_bytes + 255) & ~(size_t)255;

    long long mean_per_bucket = (Etot + nbuckets - 1) / nbuckets;
    long long min_cap = mean_per_bucket + 1600;   // ~12 sigma for binomial load
    long long cap_avail =
        ((long long)ws_size - (long long)off_rec) / ((long long)nbuckets * 16);

    constexpr int SPAN = BLK * KPT;   // 2048
    int g0 = (int)((E2 + SPAN - 1) / SPAN);
    int g1 = (int)((ES + SPAN - 1) / SPAN);
    int g2g = (int)((E3 + SPAN - 1) / SPAN);

    if (nbuckets <= NB_MAX && cap_avail >= min_cap) {
        long long capL = min_cap + 4096;
        if (capL > cap_avail) capL = cap_avail;
        int cap = (int)capL;
        int* gcount = (int*)d_ws;
        unsigned* nets = (unsigned*)((char*)d_ws + off_nets);
        float4* x4 = (float4*)((char*)d_ws + off_x4);
        float4* records = (float4*)((char*)d_ws + off_rec);

        int nb_pad = (n_nodes + 255) / 256;
        setup_kernel<<<3 + nb_pad, 256, 0, stream>>>(
            x, n_nodes, x4, gcount,
            W1_2b, b1_2b, W2_2b, b2_2b,
            W1_s,  b1_s,  W2_s,  b2_s,
            W1_3b, b1_3b, W2_3b, b2_3b,
            nets);

        p1_edge_kernel<<<g0 + g1 + g2g, 256, 0, stream>>>(
            x4,
            e2, E2, a2,
            es, ES, as,
            e3, E3, a3,
            g0, g1,
            nets, records, gcount, cap);

        p2_bucket<<<nbuckets, 1024, 0, stream>>>(records, gcount, cap, n_nodes, out);
    } else {
        hipMemsetAsync(out, 0, (size_t)out_size * sizeof(float), stream);
        constexpr int FB_BLK = 256, FB_KPT = 4;
        const long long per_blk = (long long)FB_BLK * FB_KPT;
        int a2g = (int)((E2 + per_blk - 1) / per_blk);
        int a3g = (int)((E3 + per_blk - 1) / per_blk);
        int asg = (int)((ES + per_blk - 1) / per_blk);
        if (a2g > 0)
            edge_mlp_atomic<3, FB_KPT><<<a2g, FB_BLK, 0, stream>>>(
                x, e2, E2, a2, W1_2b, b1_2b, W2_2b, b2_2b, out);
        if (a3g > 0)
            edge_mlp_atomic<6, FB_KPT><<<a3g, FB_BLK, 0, stream>>>(
                x, e3, E3, a3, W1_3b, b1_3b, W2_3b, b2_3b, out);
        if (asg > 0)
            edge_mlp_atomic<3, FB_KPT><<<asg, FB_BLK, 0, stream>>>(
                x, es, ES, as, W1_s, b1_s, W2_s, b2_s, out);
    }
}

// Round 9
// 282.375 us; speedup vs baseline: 1.0656x; 1.0656x over previous
//
#include <hip/hip_runtime.h>

// HIGNN, round 23 = R21 (285us best, p1=106) with p2 MLP-fix:
//  - p1: reverted to R21 exact (KPT=4; R22's KPT=8 cost 2x occupancy -> +17us).
//  - p2: 4-deep load ILP. Diagnosis: p2 ~65us >> 8us traffic cost; R22 showed
//    LDS atomics NOT the bottleneck (wave-private tiles = no change). Each
//    block had ~1 outstanding 16B load/thread against ~900cy HBM latency
//    (~13GB/s/block). Read 4 independent records before processing -> 4x MLP.
// LESSONS: agent fences per block = 6x poison (R19/20); global fp32 atomics
// to shared out = HBM RMW (R18); weights belong in LDS (R15); KPT=8 occupancy
// cliff (R22).

constexpr int HIDDEN = 64;
constexpr int NB_MAX = 256;      // bucket bins (>= nbuckets), == BLK
constexpr int NPB_SHIFT = 9;     // 512 nodes per bucket
constexpr int NPB = 1 << NPB_SHIFT;
constexpr int TILE_F = NPB * 3;  // floats per bucket tile (1536)
constexpr int NET_SLOT = 1040;   // dwords per packed-net slot
constexpr int BLK = 256;
constexpr int KPT = 4;

typedef _Float16 h2_t __attribute__((ext_vector_type(2)));

__device__ __forceinline__ unsigned packh2(float a, float b) {
    auto h = __builtin_amdgcn_cvt_pkrtz(a, b);   // __fp16 ext_vector(2)
    return __builtin_bit_cast(unsigned, h);
}
__device__ __forceinline__ float fdot2u(unsigned a, unsigned b, float c) {
    h2_t ha = __builtin_bit_cast(h2_t, a);
    h2_t hb = __builtin_bit_cast(h2_t, b);
#if __has_builtin(__builtin_amdgcn_fdot2)
    return __builtin_amdgcn_fdot2(ha, hb, c, false);
#else
    return fmaf((float)ha.x, (float)hb.x, fmaf((float)ha.y, (float)hb.y, c));
#endif
}

// Packed net slot layout (dword indices within NET_SLOT):
// din3 nets (2body, self): row per hh2 at h2*16 (64B aligned):
//   [0]=wA  [1]=wB  [2]=b1A f32  [3]=b1B f32  [4]=w1cA f32  [5]=w1cB f32
//   [6..14]=w2p[0..8] packed     [15]=pad
// din6 net (3body): row per hh2 at h2*32 (128B aligned):
//   [0..2]=wA0..2  [3..5]=wB0..2  [6]=b1A  [7]=b1B  [8..16]=w2p  [17..31]=pad
// all nets: [1024..1032] = b2[0..8] f32

// ---------------- Setup: pack 3 nets + zero gcount + pad x ----------------
__global__ __launch_bounds__(256) void setup_kernel(
    const float* __restrict__ x, int n_nodes, float4* __restrict__ x4,
    int* __restrict__ gcount,
    const float* __restrict__ W1_2b, const float* __restrict__ b1_2b,
    const float* __restrict__ W2_2b, const float* __restrict__ b2_2b,
    const float* __restrict__ W1_s,  const float* __restrict__ b1_s,
    const float* __restrict__ W2_s,  const float* __restrict__ b2_s,
    const float* __restrict__ W1_3b, const float* __restrict__ b1_3b,
    const float* __restrict__ W2_3b, const float* __restrict__ b2_3b,
    unsigned* __restrict__ nets)
{
    const int blk = blockIdx.x;
    const int tid = threadIdx.x;
    if (blk < 3) {
        const float *W1, *b1, *W2, *b2; int din;
        if (blk == 0) { W1 = W1_2b; b1 = b1_2b; W2 = W2_2b; b2 = b2_2b; din = 3; }
        else if (blk == 1) { W1 = W1_s; b1 = b1_s; W2 = W2_s; b2 = b2_s; din = 3; }
        else { W1 = W1_3b; b1 = b1_3b; W2 = W2_3b; b2 = b2_3b; din = 6; }
        unsigned* slot = nets + blk * NET_SLOT;
        float* slotf = (float*)slot;
        if (tid < 32) {
            const int h2 = tid, hA = 2 * h2, hB = 2 * h2 + 1;
            if (din == 3) {
                unsigned* row = slot + h2 * 16;
                float* rowf = (float*)row;
                row[0] = packh2(W1[0 * HIDDEN + hA], W1[1 * HIDDEN + hA]);
                row[1] = packh2(W1[0 * HIDDEN + hB], W1[1 * HIDDEN + hB]);
                rowf[2] = b1[hA]; rowf[3] = b1[hB];
                rowf[4] = W1[2 * HIDDEN + hA]; rowf[5] = W1[2 * HIDDEN + hB];
                #pragma unroll
                for (int i = 0; i < 9; ++i)
                    row[6 + i] = packh2(W2[hA * 9 + i], W2[hB * 9 + i]);
                row[15] = 0;
            } else {
                unsigned* row = slot + h2 * 32;
                float* rowf = (float*)row;
                #pragma unroll
                for (int r = 0; r < 3; ++r) {
                    row[r]     = packh2(W1[(2 * r) * HIDDEN + hA], W1[(2 * r + 1) * HIDDEN + hA]);
                    row[3 + r] = packh2(W1[(2 * r) * HIDDEN + hB], W1[(2 * r + 1) * HIDDEN + hB]);
                }
                rowf[6] = b1[hA]; rowf[7] = b1[hB];
                #pragma unroll
                for (int i = 0; i < 9; ++i)
                    row[8 + i] = packh2(W2[hA * 9 + i], W2[hB * 9 + i]);
                #pragma unroll
                for (int i = 17; i < 20; ++i) row[i] = 0;
            }
        }
        if (tid >= 32 && tid < 41) slotf[1024 + (tid - 32)] = b2[tid - 32];
        if (blk == 0) gcount[tid] = 0;   // zeroes all NB_MAX bins
    } else {
        int i = (blk - 3) * 256 + tid;
        if (i < n_nodes)
            x4[i] = make_float4(x[3 * i], x[3 * i + 1], x[3 * i + 2], 0.0f);
    }
}

// ---------------- Phase 1: MLP -> rank -> reserve -> append ----------------
__global__ __launch_bounds__(256) void p1_edge_kernel(
    const float4* __restrict__ x4,
    const int* __restrict__ e0, long long E0, const float* __restrict__ at0,
    const int* __restrict__ e1, long long E1, const float* __restrict__ at1,
    const int* __restrict__ e2, long long E2, const float* __restrict__ at2,
    int g0, int g1,
    const unsigned* __restrict__ nets,
    float4* __restrict__ records, int* __restrict__ gcount, int cap)
{
    static_assert(NB_MAX == BLK, "one reserve bin per thread");
    __shared__ __align__(16) unsigned s_net[1033];   // rows + b2, ~4.1 KB
    __shared__ int s_rank[NB_MAX];
    __shared__ int s_base[NB_MAX];

    // ---- parity-interleaved block -> (set, tile) mapping ----
    const int gA = g0 + g1;
    const int gB = (int)gridDim.x - gA;
    const int mn = (gA < gB) ? gA : gB;
    int aidx = -1, b6 = -1;
    {
        const int idx = blockIdx.x;
        if (idx < 2 * mn) { if (idx & 1) b6 = idx >> 1; else aidx = idx >> 1; }
        else {
            const int r = idx - 2 * mn;
            if (gA > gB) aidx = mn + r; else b6 = mn + r;
        }
    }

    const int* edges; long long E; const float* attr;
    int bidx, nblk, din3;
    const unsigned* wp;
    if (aidx >= 0) {
        if (aidx < g0) { edges = e0; E = E0; attr = at0; bidx = aidx;      nblk = g0; din3 = 1; wp = nets; }
        else           { edges = e1; E = E1; attr = at1; bidx = aidx - g0; nblk = g1; din3 = 1; wp = nets + NET_SLOT; }
    } else             { edges = e2; E = E2; attr = at2; bidx = b6;        nblk = gB; din3 = 0; wp = nets + 2 * NET_SLOT; }

    const int tid = threadIdx.x;
    long long span = (E + nblk - 1) / nblk;
    span = (span + 1023) & ~1023LL;
    const long long lo = (long long)bidx * span;
    const long long hi = (lo + span < E) ? (lo + span) : E;
    if (lo >= E) return;

    const bool e_aligned = ((E & 3) == 0);

    s_rank[tid] = 0;
    const int nstage = din3 ? 512 : 1024;
    for (int i = tid; i < nstage; i += BLK) s_net[i] = wp[i];
    if (tid < 9) s_net[1024 + tid] = wp[1024 + tid];
    __syncthreads();

    const unsigned* w = s_net;
    const float* wf = (const float*)s_net;
    float b2r[9];
    #pragma unroll
    for (int i = 0; i < 9; ++i) b2r[i] = wf[1024 + i];

    const long long be = lo + (long long)tid * KPT;   // 4-aligned

    unsigned dp[KPT][3];
    float    d2s[KPT];
    float    a[KPT][3];
    int      dst[KPT];
    bool     valid[KPT];
    int      i0[KPT], i1[KPT], i2[KPT];

    const bool lane_live = (be < hi);
    const bool full = lane_live && e_aligned && (be + KPT <= hi);
    if (full) {
        int4 r0 = *(const int4*)(edges + be);
        int4 r1 = *(const int4*)(edges + E + be);
        i0[0] = r0.x; i0[1] = r0.y; i0[2] = r0.z; i0[3] = r0.w;
        i1[0] = r1.x; i1[1] = r1.y; i1[2] = r1.z; i1[3] = r1.w;
        if (!din3) {
            int4 r2 = *(const int4*)(edges + 2 * E + be);
            i2[0] = r2.x; i2[1] = r2.y; i2[2] = r2.z; i2[3] = r2.w;
        }
        float4 a0 = *(const float4*)(attr + 3 * be);
        float4 a1 = *(const float4*)(attr + 3 * be + 4);
        float4 a2 = *(const float4*)(attr + 3 * be + 8);
        a[0][0] = a0.x; a[0][1] = a0.y; a[0][2] = a0.z;
        a[1][0] = a0.w; a[1][1] = a1.x; a[1][2] = a1.y;
        a[2][0] = a1.z; a[2][1] = a1.w; a[2][2] = a2.x;
        a[3][0] = a2.y; a[3][1] = a2.z; a[3][2] = a2.w;
        #pragma unroll
        for (int u = 0; u < KPT; ++u) valid[u] = true;
    } else {
        #pragma unroll
        for (int u = 0; u < KPT; ++u) {
            long long e = be + u;
            valid[u] = lane_live && (e < hi);
            long long ee = valid[u] ? e : lo;
            i0[u] = edges[ee];
            i1[u] = edges[E + ee];
            if (!din3) i2[u] = edges[2 * E + ee];
            #pragma unroll
            for (int c = 0; c < 3; ++c) a[u][c] = attr[3 * ee + c];
        }
    }

    // compute UNGUARDED (clamped lanes produce garbage; append is guarded)
    #pragma unroll
    for (int u = 0; u < KPT; ++u) {
        if (din3) {
            dst[u] = i1[u];
            float4 xs = x4[i0[u]];
            float4 xt = x4[i1[u]];
            dp[u][0] = packh2(xs.x - xt.x, xs.y - xt.y);
            d2s[u]   = xs.z - xt.z;
            dp[u][1] = 0; dp[u][2] = 0;
        } else {
            dst[u] = i2[u];
            float4 xj = x4[i0[u]];
            float4 xk = x4[i1[u]];
            float4 xi = x4[i2[u]];
            dp[u][0] = packh2(xk.x - xj.x, xk.y - xj.y);
            dp[u][1] = packh2(xk.z - xj.z, xi.x - xk.x);
            dp[u][2] = packh2(xi.y - xk.y, xi.z - xk.z);
            d2s[u] = 0.f;
        }
    }

    float acc[KPT][9];
    #pragma unroll
    for (int u = 0; u < KPT; ++u)
        #pragma unroll
        for (int i = 0; i < 9; ++i) acc[u][i] = b2r[i];

    if (din3) {
        #pragma unroll 2
        for (int hh2 = 0; hh2 < HIDDEN / 2; ++hh2) {
            const uint4* rq = (const uint4*)(w + (hh2 << 4));
            const uint4 q0 = rq[0], q1 = rq[1], q2 = rq[2], q3 = rq[3];
            const unsigned wA = q0.x;
            const unsigned wB = q0.y;
            const float bbA = __uint_as_float(q0.z);
            const float bbB = __uint_as_float(q0.w);
            const float wcA = __uint_as_float(q1.x);
            const float wcB = __uint_as_float(q1.y);
            const unsigned w2p[9] = {q1.z, q1.w, q2.x, q2.y, q2.z,
                                     q2.w, q3.x, q3.y, q3.z};
            #pragma unroll
            for (int u = 0; u < KPT; ++u) {
                float preA = fmaf(d2s[u], wcA, fdot2u(dp[u][0], wA, bbA));
                float preB = fmaf(d2s[u], wcB, fdot2u(dp[u][0], wB, bbB));
                unsigned h2 = packh2(fmaxf(preA, 0.f), fmaxf(preB, 0.f));
                #pragma unroll
                for (int i = 0; i < 9; ++i)
                    acc[u][i] = fdot2u(h2, w2p[i], acc[u][i]);
            }
        }
    } else {
        #pragma unroll 2
        for (int hh2 = 0; hh2 < HIDDEN / 2; ++hh2) {
            const uint4* rq = (const uint4*)(w + (hh2 << 5));
            const uint4 q0 = rq[0], q1 = rq[1], q2 = rq[2], q3 = rq[3];
            const unsigned q4x = w[(hh2 << 5) + 16];
            const unsigned wA0 = q0.x, wA1 = q0.y, wA2 = q0.z;
            const unsigned wB0 = q0.w, wB1 = q1.x, wB2 = q1.y;
            const float bbA = __uint_as_float(q1.z);
            const float bbB = __uint_as_float(q1.w);
            const unsigned w2p[9] = {q2.x, q2.y, q2.z, q2.w, q3.x,
                                     q3.y, q3.z, q3.w, q4x};
            #pragma unroll
            for (int u = 0; u < KPT; ++u) {
                float preA = fdot2u(dp[u][2], wA2,
                             fdot2u(dp[u][1], wA1,
                             fdot2u(dp[u][0], wA0, bbA)));
                float preB = fdot2u(dp[u][2], wB2,
                             fdot2u(dp[u][1], wB1,
                             fdot2u(dp[u][0], wB0, bbB)));
                unsigned h2 = packh2(fmaxf(preA, 0.f), fmaxf(preB, 0.f));
                #pragma unroll
                for (int i = 0; i < 9; ++i)
                    acc[u][i] = fdot2u(h2, w2p[i], acc[u][i]);
            }
        }
    }

    // rank: LDS atomics count per-bucket totals as a side effect
    int rk[KPT]; int bb[KPT];
    #pragma unroll
    for (int u = 0; u < KPT; ++u) {
        if (valid[u]) {
            bb[u] = dst[u] >> NPB_SHIFT;
            rk[u] = atomicAdd(&s_rank[bb[u]], 1);
        }
    }
    __syncthreads();

    // reserve per nonempty bin (one thread per bin), publish bases
    {
        int c = s_rank[tid];
        s_base[tid] = (c > 0) ? atomicAdd(&gcount[tid], c) : 0;
    }
    __syncthreads();

    #pragma unroll
    for (int u = 0; u < KPT; ++u) {
        if (!valid[u]) continue;
        float y0 = fmaf(acc[u][0], a[u][0], fmaf(acc[u][1], a[u][1], acc[u][2] * a[u][2]));
        float y1 = fmaf(acc[u][3], a[u][0], fmaf(acc[u][4], a[u][1], acc[u][5] * a[u][2]));
        float y2 = fmaf(acc[u][6], a[u][0], fmaf(acc[u][7], a[u][1], acc[u][8] * a[u][2]));
        int slot = s_base[bb[u]] + rk[u];
        if (slot < cap)
            records[(size_t)bb[u] * cap + slot] =
                make_float4(y0, y1, y2, __int_as_float(dst[u]));
    }
}

// ---------------- Phase 2: one block per bucket, 4-deep load ILP ----------------
__global__ __launch_bounds__(1024) void p2_bucket(
    const float4* __restrict__ records, const int* __restrict__ gcount,
    int cap, int n_nodes, float* __restrict__ out)
{
    __shared__ float s_acc[TILE_F];   // 6 KB
    const int b = blockIdx.x;
    const int tid = threadIdx.x;

    for (int i = tid; i < TILE_F; i += 1024) s_acc[i] = 0.0f;
    __syncthreads();

    int cnt = gcount[b];
    if (cnt > cap) cnt = cap;
    const float4* rb = records + (size_t)b * cap;

    // 4-deep ILP: 4 independent 16B loads in flight before any LDS work.
    int i = tid;
    for (; i + 3 * 1024 < cnt; i += 4 * 1024) {
        float4 r0 = rb[i];
        float4 r1 = rb[i + 1024];
        float4 r2 = rb[i + 2048];
        float4 r3 = rb[i + 3072];
        int l0 = __float_as_int(r0.w) - (b << NPB_SHIFT);
        int l1 = __float_as_int(r1.w) - (b << NPB_SHIFT);
        int l2 = __float_as_int(r2.w) - (b << NPB_SHIFT);
        int l3 = __float_as_int(r3.w) - (b << NPB_SHIFT);
        atomicAdd(&s_acc[l0 * 3 + 0], r0.x);
        atomicAdd(&s_acc[l0 * 3 + 1], r0.y);
        atomicAdd(&s_acc[l0 * 3 + 2], r0.z);
        atomicAdd(&s_acc[l1 * 3 + 0], r1.x);
        atomicAdd(&s_acc[l1 * 3 + 1], r1.y);
        atomicAdd(&s_acc[l1 * 3 + 2], r1.z);
        atomicAdd(&s_acc[l2 * 3 + 0], r2.x);
        atomicAdd(&s_acc[l2 * 3 + 1], r2.y);
        atomicAdd(&s_acc[l2 * 3 + 2], r2.z);
        atomicAdd(&s_acc[l3 * 3 + 0], r3.x);
        atomicAdd(&s_acc[l3 * 3 + 1], r3.y);
        atomicAdd(&s_acc[l3 * 3 + 2], r3.z);
    }
    for (; i < cnt; i += 1024) {
        float4 r = rb[i];
        int loc = __float_as_int(r.w) - (b << NPB_SHIFT);
        atomicAdd(&s_acc[loc * 3 + 0], r.x);
        atomicAdd(&s_acc[loc * 3 + 1], r.y);
        atomicAdd(&s_acc[loc * 3 + 2], r.z);
    }
    __syncthreads();

    const int start = (b << NPB_SHIFT) * 3;
    const int end = min(n_nodes * 3, ((b + 1) << NPB_SHIFT) * 3);
    for (int i2 = start + tid; i2 < end; i2 += 1024)
        out[i2] = s_acc[i2 - start];
}

// ---------------- Fallback: direct device atomics, fp32 ----------------
template <int DIN, int KPTF>
__global__ __launch_bounds__(256) void edge_mlp_atomic(
    const float* __restrict__ x,
    const int* __restrict__ edges, long long E,
    const float* __restrict__ attr,
    const float* __restrict__ W1, const float* __restrict__ b1,
    const float* __restrict__ W2, const float* __restrict__ b2,
    float* __restrict__ out)
{
    const int tid = threadIdx.x;
    const long long base = (long long)blockIdx.x * (blockDim.x * KPTF) + tid;
    float d[KPTF][DIN]; float a[KPTF][3]; int dst[KPTF]; bool valid[KPTF];
    #pragma unroll
    for (int u = 0; u < KPTF; ++u) {
        long long e = base + (long long)u * blockDim.x;
        valid[u] = (e < E);
        long long ee = valid[u] ? e : 0;
        if constexpr (DIN == 3) {
            int s = edges[ee]; int t = edges[E + ee]; dst[u] = t;
            #pragma unroll
            for (int c = 0; c < 3; ++c)
                d[u][c] = x[3 * (long long)s + c] - x[3 * (long long)t + c];
        } else {
            int j = edges[ee]; int k = edges[E + ee]; int i = edges[2 * E + ee];
            dst[u] = i;
            #pragma unroll
            for (int c = 0; c < 3; ++c) {
                float xj = x[3 * (long long)j + c];
                float xk = x[3 * (long long)k + c];
                float xi = x[3 * (long long)i + c];
                d[u][c] = xk - xj; d[u][3 + c] = xi - xk;
            }
        }
        #pragma unroll
        for (int c = 0; c < 3; ++c) a[u][c] = attr[3 * ee + c];
    }
    float acc[KPTF][9];
    #pragma unroll
    for (int u = 0; u < KPTF; ++u)
        #pragma unroll
        for (int i = 0; i < 9; ++i) acc[u][i] = b2[i];
    #pragma unroll 4
    for (int hh = 0; hh < HIDDEN; ++hh) {
        const float bb = b1[hh];
        float w1r[DIN];
        #pragma unroll
        for (int r = 0; r < DIN; ++r) w1r[r] = W1[r * HIDDEN + hh];
        float w2r[9];
        #pragma unroll
        for (int i = 0; i < 9; ++i) w2r[i] = W2[hh * 9 + i];
        #pragma unroll
        for (int u = 0; u < KPTF; ++u) {
            float pre = bb;
            #pragma unroll
            for (int r = 0; r < DIN; ++r) pre = fmaf(d[u][r], w1r[r], pre);
            const float h = fmaxf(pre, 0.0f);
            #pragma unroll
            for (int i = 0; i < 9; ++i) acc[u][i] = fmaf(h, w2r[i], acc[u][i]);
        }
    }
    #pragma unroll
    for (int u = 0; u < KPTF; ++u) {
        if (!valid[u]) continue;
        float* o = out + 3 * (long long)dst[u];
        #pragma unroll
        for (int i = 0; i < 3; ++i) {
            float y = fmaf(acc[u][3 * i + 0], a[u][0],
                      fmaf(acc[u][3 * i + 1], a[u][1],
                           acc[u][3 * i + 2] * a[u][2]));
            atomicAdd(&o[i], y);
        }
    }
}

extern "C" void kernel_launch(void* const* d_in, const int* in_sizes, int n_in,
                              void* d_out, int out_size, void* d_ws, size_t ws_size,
                              hipStream_t stream)
{
    const float* x  = (const float*)d_in[0];
    const int*   e2 = (const int*)d_in[1];
    const int*   e3 = (const int*)d_in[2];
    const int*   es = (const int*)d_in[3];
    const float* a2 = (const float*)d_in[5];
    const float* a3 = (const float*)d_in[6];
    const float* as = (const float*)d_in[7];
    const float* W1_2b = (const float*)d_in[9];
    const float* b1_2b = (const float*)d_in[10];
    const float* W2_2b = (const float*)d_in[11];
    const float* b2_2b = (const float*)d_in[12];
    const float* W1_3b = (const float*)d_in[13];
    const float* b1_3b = (const float*)d_in[14];
    const float* W2_3b = (const float*)d_in[15];
    const float* b2_3b = (const float*)d_in[16];
    const float* W1_s  = (const float*)d_in[17];
    const float* b1_s  = (const float*)d_in[18];
    const float* W2_s  = (const float*)d_in[19];
    const float* b2_s  = (const float*)d_in[20];

    const long long E2 = in_sizes[1] / 2;
    const long long E3 = in_sizes[2] / 3;
    const long long ES = in_sizes[3] / 2;
    const long long Etot = E2 + E3 + ES;
    const int n_nodes = out_size / 3;
    const int nbuckets = (n_nodes + NPB - 1) >> NPB_SHIFT;

    float* out = (float*)d_out;

    // ws layout: [gcount 1KB][nets][x4][records]
    const size_t off_nets = 1024;
    const size_t off_x4 = (off_nets + 3 * NET_SLOT * 4 + 255) & ~(size_t)255;
    const size_t x4_bytes = (size_t)n_nodes * sizeof(float4);
    const size_t off_rec = (off_x4 + x4_bytes + 255) & ~(size_t)255;

    long long mean_per_bucket = (Etot + nbuckets - 1) / nbuckets;
    long long min_cap = mean_per_bucket + 1600;   // ~12 sigma for binomial load
    long long cap_avail =
        ((long long)ws_size - (long long)off_rec) / ((long long)nbuckets * 16);

    constexpr int SPAN = 1024;    // one tile per block (BLK*KPT)
    int g0 = (int)((E2 + SPAN - 1) / SPAN);
    int g1 = (int)((ES + SPAN - 1) / SPAN);
    int g2g = (int)((E3 + SPAN - 1) / SPAN);

    if (nbuckets <= NB_MAX && cap_avail >= min_cap) {
        long long capL = min_cap + 4096;
        if (capL > cap_avail) capL = cap_avail;
        int cap = (int)capL;
        int* gcount = (int*)d_ws;
        unsigned* nets = (unsigned*)((char*)d_ws + off_nets);
        float4* x4 = (float4*)((char*)d_ws + off_x4);
        float4* records = (float4*)((char*)d_ws + off_rec);

        int nb_pad = (n_nodes + 255) / 256;
        setup_kernel<<<3 + nb_pad, 256, 0, stream>>>(
            x, n_nodes, x4, gcount,
            W1_2b, b1_2b, W2_2b, b2_2b,
            W1_s,  b1_s,  W2_s,  b2_s,
            W1_3b, b1_3b, W2_3b, b2_3b,
            nets);

        p1_edge_kernel<<<g0 + g1 + g2g, 256, 0, stream>>>(
            x4,
            e2, E2, a2,
            es, ES, as,
            e3, E3, a3,
            g0, g1,
            nets, records, gcount, cap);

        p2_bucket<<<nbuckets, 1024, 0, stream>>>(records, gcount, cap, n_nodes, out);
    } else {
        hipMemsetAsync(out, 0, (size_t)out_size * sizeof(float), stream);
        constexpr int FB_BLK = 256, FB_KPT = 4;
        const long long per_blk = (long long)FB_BLK * FB_KPT;
        int a2g = (int)((E2 + per_blk - 1) / per_blk);
        int a3g = (int)((E3 + per_blk - 1) / per_blk);
        int asg = (int)((ES + per_blk - 1) / per_blk);
        if (a2g > 0)
            edge_mlp_atomic<3, FB_KPT><<<a2g, FB_BLK, 0, stream>>>(
                x, e2, E2, a2, W1_2b, b1_2b, W2_2b, b2_2b, out);
        if (a3g > 0)
            edge_mlp_atomic<6, FB_KPT><<<a3g, FB_BLK, 0, stream>>>(
                x, e3, E3, a3, W1_3b, b1_3b, W2_3b, b2_3b, out);
        if (asg > 0)
            edge_mlp_atomic<3, FB_KPT><<<asg, FB_BLK, 0, stream>>>(
                x, es, ES, as, W1_s, b1_s, W2_s, b2_s, out);
    }
}